// Round 16
// baseline (409.535 us; speedup 1.0000x reference)
//
#include <hip/hip_runtime.h>
#include <math.h>

typedef float f32x4 __attribute__((ext_vector_type(4)));
typedef __bf16 bf16x8 __attribute__((ext_vector_type(8)));
typedef unsigned int u32;
typedef u32 u32x4 __attribute__((ext_vector_type(4)));

#define AS1 __attribute__((address_space(1)))
#define AS3 __attribute__((address_space(3)))

static __device__ __forceinline__ void gload16(const void* g, void* l) {
    __builtin_amdgcn_global_load_lds((const AS1 u32*)g, (AS3 u32*)l, 16, 0, 0);
}
static __device__ __forceinline__ f32x4 mfma16(bf16x8 a, bf16x8 b, f32x4 c) {
    return __builtin_amdgcn_mfma_f32_16x16x32_bf16(a, b, c, 0, 0, 0);
}
static __device__ __forceinline__ float exp2fast(float x) {
    return __builtin_amdgcn_exp2f(x);
}

// ---------------------------------------------------------------------------
// fused fp32 -> bf16 convert over 3 segments
// ---------------------------------------------------------------------------
__global__ __launch_bounds__(256)
void convert3_kernel(const float* __restrict__ in0, __bf16* __restrict__ out0, int nb0,
                     const float* __restrict__ in1, __bf16* __restrict__ out1, int nb1,
                     const float* __restrict__ in2, __bf16* __restrict__ out2)
{
    int b = blockIdx.x;
    const float* in; __bf16* out;
    if (b < nb0)            { in = in0; out = out0; }
    else if (b < nb0 + nb1) { in = in1; out = out1; b -= nb0; }
    else                    { in = in2; out = out2; b -= nb0 + nb1; }
    const size_t i = ((size_t)b * 256 + threadIdx.x) * 8;
    f32x4 a = *(const f32x4*)(in + i);
    f32x4 c = *(const f32x4*)(in + i + 4);
    bf16x8 o;
    #pragma unroll
    for (int j = 0; j < 4; ++j) { o[j] = (__bf16)a[j]; o[j + 4] = (__bf16)c[j]; }
    *(bf16x8*)(out + i) = o;
}

// ---------------------------------------------------------------------------
// GEMM 256M x 128N, BK=64, 8 waves, single-buffer 48KB LDS, 2-barrier m97
// skeleton (R8 proven optimum: 3 blocks/CU; at the measured 12.6 B/cy/CU
// LDS-fill duty ceiling). MODE 0: super-tiled 5x4 order; q,k -> qkv,
// V direct-transposed to vt. MODE 1: -> f32 out.
// ---------------------------------------------------------------------------
template<int MODE>
__global__ __launch_bounds__(512)
void gemm_big(const __bf16* __restrict__ A, const __bf16* __restrict__ Bw,
              const float* __restrict__ bias, __bf16* __restrict__ qkv,
              __bf16* __restrict__ vt, float* __restrict__ f_out)
{
    constexpr int M = 16400;
    constexpr int K = 1024;
    constexpr int NBX = (MODE == 0) ? 24 : 8;
    constexpr int NOUT = (MODE == 0) ? 3072 : 1024;
    constexpr int CHUNK = (65 * NBX) / 8;

    __shared__ __align__(16) __bf16 As[256 * 64];
    __shared__ __align__(16) __bf16 Bs[128 * 64];

    const int tid  = threadIdx.x;
    const int lane = tid & 63;
    const int wv   = tid >> 6;
    const int wrm  = wv >> 1;
    const int wcn  = wv & 1;
    const int fr   = lane & 15, fq = lane >> 4;

    const int xx = blockIdx.x & 7, jj = blockIdx.x >> 3;
    const int g  = xx * CHUNK + jj;
    int by, bx;
    if constexpr (MODE == 0) {
        const int s = g / 20, r = g % 20;
        by = (s / 6) * 5 + (r >> 2);
        bx = (s % 6) * 4 + (r & 3);
    } else {
        by = g / NBX; bx = g % NBX;
    }
    const int m0 = by * 256, n0 = bx * 128;

    const __bf16* aptr[4]; int aoff[4];
    #pragma unroll
    for (int qd = 0; qd < 4; ++qd) {
        const int s = qd * 512 + tid;
        const int r = s >> 3;
        const int c = (s & 7) ^ (r & 7);
        aoff[qd] = s * 8;
        int ar = m0 + r; if (ar > M - 1) ar = M - 1;
        aptr[qd] = A + (size_t)ar * K + c * 8;
    }
    const __bf16* bptr[2]; int boff[2];
    #pragma unroll
    for (int l = 0; l < 2; ++l) {
        const int s = l * 512 + tid;
        const int r = s >> 3;
        const int c = (s & 7) ^ (r & 7);
        boff[l] = s * 8;
        bptr[l] = Bw + (size_t)(n0 + r) * K + c * 8;
    }

    f32x4 acc[4][4];
    #pragma unroll
    for (int i = 0; i < 4; ++i)
        #pragma unroll
        for (int j = 0; j < 4; ++j)
            acc[i][j] = f32x4{0.f, 0.f, 0.f, 0.f};

    for (int kt = 0; kt < K / 64; ++kt) {
        const int kof = kt * 64;
        #pragma unroll
        for (int qd = 0; qd < 4; ++qd) gload16(aptr[qd] + kof, &As[aoff[qd]]);
        #pragma unroll
        for (int l = 0; l < 2; ++l)   gload16(bptr[l] + kof, &Bs[boff[l]]);
        __syncthreads();

        #pragma unroll
        for (int ks = 0; ks < 2; ++ks) {
            bf16x8 a[4], b[4];
            #pragma unroll
            for (int i = 0; i < 4; ++i) {
                const int ra = wrm * 64 + i * 16 + fr;
                const int rb = wcn * 64 + i * 16 + fr;
                a[i] = *(const bf16x8*)&As[ra * 64 + ((ks * 4 + fq) ^ (ra & 7)) * 8];
                b[i] = *(const bf16x8*)&Bs[rb * 64 + ((ks * 4 + fq) ^ (rb & 7)) * 8];
            }
            #pragma unroll
            for (int i = 0; i < 4; ++i)
                #pragma unroll
                for (int j = 0; j < 4; ++j)
                    acc[i][j] = mfma16(a[i], b[j], acc[i][j]);
        }
        __syncthreads();
    }

    #pragma unroll
    for (int ni = 0; ni < 4; ++ni) {
        const int col = n0 + wcn * 64 + ni * 16 + fr;
        const float bv = bias[col];
        if constexpr (MODE == 0) {
            const int tsel = (col >> 6) % 3;
            if (tsel < 2) {
                const float scale = (tsel == 0) ? 0.18033688011112042f : 1.0f;
                #pragma unroll
                for (int mi = 0; mi < 4; ++mi) {
                    #pragma unroll
                    for (int j = 0; j < 4; ++j) {
                        const int m = m0 + wrm * 64 + mi * 16 + fq * 4 + j;
                        if (m < M)
                            qkv[(size_t)m * 3072 + col] =
                                (__bf16)((acc[mi][ni][j] + bv) * scale);
                    }
                }
            } else {
                const int head = col / 192;
                const int d    = col & 63;
                #pragma unroll
                for (int mi = 0; mi < 4; ++mi) {
                    #pragma unroll
                    for (int j = 0; j < 4; ++j) {
                        const int m = m0 + wrm * 64 + mi * 16 + fq * 4 + j;
                        if (m < M) {
                            const int bb = m / 1025;
                            const int ss = m - bb * 1025;
                            vt[((size_t)((bb * 16 + head) * 64 + d)) * 1088 + ss] =
                                (__bf16)(acc[mi][ni][j] + bv);
                        }
                    }
                }
            }
        } else {
            #pragma unroll
            for (int mi = 0; mi < 4; ++mi) {
                #pragma unroll
                for (int j = 0; j < 4; ++j) {
                    const int m = m0 + wrm * 64 + mi * 16 + fq * 4 + j;
                    if (m < M) f_out[(size_t)m * NOUT + col] = acc[mi][ni][j] + bv;
                }
            }
        }
    }
}

// ---------------------------------------------------------------------------
// Flash attention, swapped QK^T, QBLK=128, 1-barrier dbuf prefetch loop
// (R15) + IN-REGISTER P exchange replacing the Ps LDS round-trip:
//   writer (fr,fq) packs W[m]=pack(p[m>>1][2(m&1)],p[..+1]) (kv=16ni+4fq+..)
//   reader needs pav[ks][t] = W[fqw=2(fq&1)+(t>>1)][m=4ks+2(fq>>1)+(t&1)]
//   3 shfl_xor (16/32/48) per (ks,h) + selects route all 16 cases exactly.
// Removes 17KB Ps -> LDS 32KB -> 4 blocks/CU (32 waves, max) AND drops two
// LDS latency hops from the per-tile serial chain.
// ---------------------------------------------------------------------------
__global__ __launch_bounds__(512)
void attn_kernel(const __bf16* __restrict__ qkvb, const __bf16* __restrict__ vtb,
                 __bf16* __restrict__ ctxb)
{
    constexpr int S = 1025, S2 = 1088, ROW = 3072;
    const int tid  = threadIdx.x;
    const int lane = tid & 63;
    const int w    = tid >> 6;
    const int fr   = lane & 15, fq = lane >> 4;

    const int xx = blockIdx.x & 7, jj = blockIdx.x >> 3;
    const int tile = xx * 288 + jj;
    const int bh = tile / 9;
    const int q0 = (tile % 9) * 128;
    const int bb = bh >> 4, hh = bh & 15;

    const __bf16* qp = qkvb + (size_t)(bb * 1025) * ROW + hh * 192;
    const __bf16* kp = qp + 64;
    const __bf16* vp = vtb + (size_t)bh * 64 * S2;

    __shared__ __align__(16) __bf16 Ks[2][64 * 64];
    __shared__ __align__(16) __bf16 Vs[2][64 * 64];

    const int r0 = tid >> 3, g0 = (tid & 7) ^ ((tid >> 3) & 7);

#define ASTAGE(nb, kv0s) { \
    int kr = (kv0s) + r0; if (kr > S - 1) kr = S - 1; \
    gload16(kp + (size_t)kr * ROW + g0 * 8, &Ks[nb][tid * 8]); \
    gload16(vp + (size_t)r0 * S2 + (kv0s) + g0 * 8, &Vs[nb][tid * 8]); }

    int qrow = q0 + w * 16 + fr; if (qrow > S - 1) qrow = S - 1;
    const bf16x8 qa0 = *(const bf16x8*)(qp + (size_t)qrow * ROW + fq * 8);
    const bf16x8 qa1 = *(const bf16x8*)(qp + (size_t)qrow * ROW + 32 + fq * 8);

    f32x4 ctx[4];
    #pragma unroll
    for (int di = 0; di < 4; ++di) ctx[di] = f32x4{0.f, 0.f, 0.f, 0.f};
    float mrow = -1e30f;
    float lrow = 0.f;

    const bool hi2 = ((fq >> 1) & 1) != 0;   // fq in {2,3}

    ASTAGE(0, 0);
    __syncthreads();

    for (int kt = 0; kt < 17; ++kt) {
        const int cur = kt & 1;
        const int kv0 = kt * 64;
        if (kt + 1 < 17) ASTAGE(cur ^ 1, kv0 + 64);   // prefetch under compute

        f32x4 sc[4];
        #pragma unroll
        for (int ni = 0; ni < 4; ++ni) {
            const int row = ni * 16 + fr;
            bf16x8 kf0 = *(const bf16x8*)&Ks[cur][row * 64 + ((fq    ) ^ (row & 7)) * 8];
            bf16x8 kf1 = *(const bf16x8*)&Ks[cur][row * 64 + ((fq + 4) ^ (row & 7)) * 8];
            f32x4 z = f32x4{0.f, 0.f, 0.f, 0.f};
            z = mfma16(kf0, qa0, z);
            sc[ni] = mfma16(kf1, qa1, z);
        }
        if (kv0 + 64 > S) {
            #pragma unroll
            for (int ni = 0; ni < 4; ++ni)
                #pragma unroll
                for (int j = 0; j < 4; ++j)
                    if (kv0 + ni * 16 + fq * 4 + j >= S) sc[ni][j] = -1e30f;
        }

        float mt = sc[0][0];
        #pragma unroll
        for (int ni = 0; ni < 4; ++ni)
            #pragma unroll
            for (int j = 0; j < 4; ++j) mt = fmaxf(mt, sc[ni][j]);
        mt = fmaxf(mt, __shfl_xor(mt, 16, 64));
        mt = fmaxf(mt, __shfl_xor(mt, 32, 64));

        if (__any(mt > mrow + 8.0f)) {
            const float mnew = fmaxf(mrow, mt);
            const float alpha = exp2fast(mrow - mnew);
            mrow = mnew;
            lrow *= alpha;
            float av[4];
            #pragma unroll
            for (int j = 0; j < 4; ++j) av[j] = __shfl(alpha, fq * 4 + j, 64);
            #pragma unroll
            for (int di = 0; di < 4; ++di) {
                ctx[di][0] *= av[0]; ctx[di][1] *= av[1];
                ctx[di][2] *= av[2]; ctx[di][3] *= av[3];
            }
        }

        float p[4][4];
        float s = 0.f;
        #pragma unroll
        for (int ni = 0; ni < 4; ++ni)
            #pragma unroll
            for (int j = 0; j < 4; ++j) {
                p[ni][j] = exp2fast(sc[ni][j] - mrow);
                s += p[ni][j];
            }
        s += __shfl_xor(s, 16, 64);
        s += __shfl_xor(s, 32, 64);
        lrow += s;

        // ---- pack own P words: W[ni*2+h] covers kv=16ni+4fq+2h,+1 ----
        u32 W[8];
        #pragma unroll
        for (int ni = 0; ni < 4; ++ni) {
            #pragma unroll
            for (int h = 0; h < 2; ++h) {
                unsigned short lo = __builtin_bit_cast(unsigned short, (__bf16)p[ni][2 * h]);
                unsigned short hb = __builtin_bit_cast(unsigned short, (__bf16)p[ni][2 * h + 1]);
                W[ni * 2 + h] = (u32)lo | ((u32)hb << 16);
            }
        }

        // ---- in-register exchange -> pav[ks][t] (verified 16-case table) ----
        u32x4 pav[2];
        #pragma unroll
        for (int ks = 0; ks < 2; ++ks) {
            #pragma unroll
            for (int h = 0; h < 2; ++h) {
                const u32 s0 = hi2 ? W[4 * ks + 2 + h] : W[4 * ks + h];
                const u32 s1 = hi2 ? W[4 * ks + h]     : W[4 * ks + 2 + h];
                const u32 A = __shfl_xor(s0, 16, 64);
                const u32 B = __shfl_xor(s1, 32, 64);
                const u32 C = __shfl_xor(s1, 48, 64);
                pav[ks][h]     = (fq == 0) ? s0 : (fq == 1) ? C : (fq == 2) ? B : A;
                pav[ks][2 + h] = (fq == 3) ? s0 : (fq == 2) ? C : (fq == 1) ? B : A;
            }
        }

        #pragma unroll
        for (int ks = 0; ks < 2; ++ks) {
            const bf16x8 pa = __builtin_bit_cast(bf16x8, pav[ks]);
            #pragma unroll
            for (int di = 0; di < 4; ++di) {
                const int row = di * 16 + fr;
                bf16x8 vf = *(const bf16x8*)&Vs[cur][row * 64 + ((ks * 4 + fq) ^ (row & 7)) * 8];
                ctx[di] = mfma16(pa, vf, ctx[di]);
            }
        }
        __syncthreads();   // single barrier: certifies nxt loads + WAR guard
    }

    float linv[4];
    #pragma unroll
    for (int j = 0; j < 4; ++j) linv[j] = 1.0f / __shfl(lrow, fq * 4 + j, 64);
    #pragma unroll
    for (int di = 0; di < 4; ++di) {
        #pragma unroll
        for (int j = 0; j < 4; ++j) {
            const int qg = q0 + w * 16 + fq * 4 + j;
            if (qg < S) {
                ctxb[((size_t)bb * 1025 + qg) * 1024 + hh * 64 + di * 16 + fr] =
                    (__bf16)(ctx[di][j] * linv[j]);
            }
        }
    }
#undef ASTAGE
}

// ---------------------------------------------------------------------------
extern "C" void kernel_launch(void* const* d_in, const int* in_sizes, int n_in,
                              void* d_out, int out_size, void* d_ws, size_t ws_size,
                              hipStream_t stream)
{
    const float* hs      = (const float*)d_in[0];
    const float* w_qkv   = (const float*)d_in[1];
    const float* b_qkv   = (const float*)d_in[2];
    const float* w_dense = (const float*)d_in[3];
    const float* b_dense = (const float*)d_in[4];

    const size_t nHS  = (size_t)16 * 1025 * 1024;
    const size_t nWQ  = (size_t)3072 * 1024;
    const size_t nWD  = (size_t)1024 * 1024;
    const size_t nQKV = (size_t)16400 * 3072;

    __bf16* hsb     = (__bf16*)d_ws;
    __bf16* wqkvb   = hsb + nHS;
    __bf16* wdenseb = wqkvb + nWQ;
    __bf16* qkvb    = wdenseb + nWD;
    __bf16* ctxb    = qkvb + nQKV;
    __bf16* vtb     = ctxb + nHS;

    convert3_kernel<<<dim3(8200 + 1536 + 512), dim3(256), 0, stream>>>(
        hs, hsb, 8200, w_qkv, wqkvb, 1536, w_dense, wdenseb);

    gemm_big<0><<<dim3(65 * 24), dim3(512), 0, stream>>>(
        hsb, wqkvb, b_qkv, qkvb, vtb, nullptr);

    attn_kernel<<<dim3(8 * 288), dim3(512), 0, stream>>>(qkvb, vtb, ctxb);

    gemm_big<1><<<dim3(65 * 8), dim3(512), 0, stream>>>(
        ctxb, wdenseb, b_dense, nullptr, nullptr, (float*)d_out);
}

// Round 17
// 380.972 us; speedup vs baseline: 1.0750x; 1.0750x over previous
//
#include <hip/hip_runtime.h>
#include <math.h>

typedef float f32x4 __attribute__((ext_vector_type(4)));
typedef __bf16 bf16x8 __attribute__((ext_vector_type(8)));
typedef unsigned int u32;
typedef u32 u32x4 __attribute__((ext_vector_type(4)));

#define AS1 __attribute__((address_space(1)))
#define AS3 __attribute__((address_space(3)))

static __device__ __forceinline__ void gload16(const void* g, void* l) {
    __builtin_amdgcn_global_load_lds((const AS1 u32*)g, (AS3 u32*)l, 16, 0, 0);
}
static __device__ __forceinline__ f32x4 mfma16(bf16x8 a, bf16x8 b, f32x4 c) {
    return __builtin_amdgcn_mfma_f32_16x16x32_bf16(a, b, c, 0, 0, 0);
}
static __device__ __forceinline__ float exp2fast(float x) {
    return __builtin_amdgcn_exp2f(x);
}

// ---------------------------------------------------------------------------
// fused fp32 -> bf16 convert over 3 segments
// ---------------------------------------------------------------------------
__global__ __launch_bounds__(256)
void convert3_kernel(const float* __restrict__ in0, __bf16* __restrict__ out0, int nb0,
                     const float* __restrict__ in1, __bf16* __restrict__ out1, int nb1,
                     const float* __restrict__ in2, __bf16* __restrict__ out2)
{
    int b = blockIdx.x;
    const float* in; __bf16* out;
    if (b < nb0)            { in = in0; out = out0; }
    else if (b < nb0 + nb1) { in = in1; out = out1; b -= nb0; }
    else                    { in = in2; out = out2; b -= nb0 + nb1; }
    const size_t i = ((size_t)b * 256 + threadIdx.x) * 8;
    f32x4 a = *(const f32x4*)(in + i);
    f32x4 c = *(const f32x4*)(in + i + 4);
    bf16x8 o;
    #pragma unroll
    for (int j = 0; j < 4; ++j) { o[j] = (__bf16)a[j]; o[j + 4] = (__bf16)c[j]; }
    *(bf16x8*)(out + i) = o;
}

// ---------------------------------------------------------------------------
// GEMM 256M x 128N, BK=64, 8 waves, single-buffer 48KB LDS, 2-barrier m97
// skeleton (R8 proven optimum: 3 blocks/CU; at the measured 12.6 B/cy/CU
// LDS-fill duty ceiling). MODE 0: super-tiled 5x4 order; q,k -> qkv,
// V direct-transposed to vt. MODE 1: -> f32 out.
// ---------------------------------------------------------------------------
template<int MODE>
__global__ __launch_bounds__(512)
void gemm_big(const __bf16* __restrict__ A, const __bf16* __restrict__ Bw,
              const float* __restrict__ bias, __bf16* __restrict__ qkv,
              __bf16* __restrict__ vt, float* __restrict__ f_out)
{
    constexpr int M = 16400;
    constexpr int K = 1024;
    constexpr int NBX = (MODE == 0) ? 24 : 8;
    constexpr int NOUT = (MODE == 0) ? 3072 : 1024;
    constexpr int CHUNK = (65 * NBX) / 8;

    __shared__ __align__(16) __bf16 As[256 * 64];
    __shared__ __align__(16) __bf16 Bs[128 * 64];

    const int tid  = threadIdx.x;
    const int lane = tid & 63;
    const int wv   = tid >> 6;
    const int wrm  = wv >> 1;
    const int wcn  = wv & 1;
    const int fr   = lane & 15, fq = lane >> 4;

    const int xx = blockIdx.x & 7, jj = blockIdx.x >> 3;
    const int g  = xx * CHUNK + jj;
    int by, bx;
    if constexpr (MODE == 0) {
        const int s = g / 20, r = g % 20;
        by = (s / 6) * 5 + (r >> 2);
        bx = (s % 6) * 4 + (r & 3);
    } else {
        by = g / NBX; bx = g % NBX;
    }
    const int m0 = by * 256, n0 = bx * 128;

    const __bf16* aptr[4]; int aoff[4];
    #pragma unroll
    for (int qd = 0; qd < 4; ++qd) {
        const int s = qd * 512 + tid;
        const int r = s >> 3;
        const int c = (s & 7) ^ (r & 7);
        aoff[qd] = s * 8;
        int ar = m0 + r; if (ar > M - 1) ar = M - 1;
        aptr[qd] = A + (size_t)ar * K + c * 8;
    }
    const __bf16* bptr[2]; int boff[2];
    #pragma unroll
    for (int l = 0; l < 2; ++l) {
        const int s = l * 512 + tid;
        const int r = s >> 3;
        const int c = (s & 7) ^ (r & 7);
        boff[l] = s * 8;
        bptr[l] = Bw + (size_t)(n0 + r) * K + c * 8;
    }

    f32x4 acc[4][4];
    #pragma unroll
    for (int i = 0; i < 4; ++i)
        #pragma unroll
        for (int j = 0; j < 4; ++j)
            acc[i][j] = f32x4{0.f, 0.f, 0.f, 0.f};

    for (int kt = 0; kt < K / 64; ++kt) {
        const int kof = kt * 64;
        #pragma unroll
        for (int qd = 0; qd < 4; ++qd) gload16(aptr[qd] + kof, &As[aoff[qd]]);
        #pragma unroll
        for (int l = 0; l < 2; ++l)   gload16(bptr[l] + kof, &Bs[boff[l]]);
        __syncthreads();

        #pragma unroll
        for (int ks = 0; ks < 2; ++ks) {
            bf16x8 a[4], b[4];
            #pragma unroll
            for (int i = 0; i < 4; ++i) {
                const int ra = wrm * 64 + i * 16 + fr;
                const int rb = wcn * 64 + i * 16 + fr;
                a[i] = *(const bf16x8*)&As[ra * 64 + ((ks * 4 + fq) ^ (ra & 7)) * 8];
                b[i] = *(const bf16x8*)&Bs[rb * 64 + ((ks * 4 + fq) ^ (rb & 7)) * 8];
            }
            #pragma unroll
            for (int i = 0; i < 4; ++i)
                #pragma unroll
                for (int j = 0; j < 4; ++j)
                    acc[i][j] = mfma16(a[i], b[j], acc[i][j]);
        }
        __syncthreads();
    }

    #pragma unroll
    for (int ni = 0; ni < 4; ++ni) {
        const int col = n0 + wcn * 64 + ni * 16 + fr;
        const float bv = bias[col];
        if constexpr (MODE == 0) {
            const int tsel = (col >> 6) % 3;
            if (tsel < 2) {
                const float scale = (tsel == 0) ? 0.18033688011112042f : 1.0f;
                #pragma unroll
                for (int mi = 0; mi < 4; ++mi) {
                    #pragma unroll
                    for (int j = 0; j < 4; ++j) {
                        const int m = m0 + wrm * 64 + mi * 16 + fq * 4 + j;
                        if (m < M)
                            qkv[(size_t)m * 3072 + col] =
                                (__bf16)((acc[mi][ni][j] + bv) * scale);
                    }
                }
            } else {
                const int head = col / 192;
                const int d    = col & 63;
                #pragma unroll
                for (int mi = 0; mi < 4; ++mi) {
                    #pragma unroll
                    for (int j = 0; j < 4; ++j) {
                        const int m = m0 + wrm * 64 + mi * 16 + fq * 4 + j;
                        if (m < M) {
                            const int bb = m / 1025;
                            const int ss = m - bb * 1025;
                            vt[((size_t)((bb * 16 + head) * 64 + d)) * 1088 + ss] =
                                (__bf16)(acc[mi][ni][j] + bv);
                        }
                    }
                }
            }
        } else {
            #pragma unroll
            for (int mi = 0; mi < 4; ++mi) {
                #pragma unroll
                for (int j = 0; j < 4; ++j) {
                    const int m = m0 + wrm * 64 + mi * 16 + fq * 4 + j;
                    if (m < M) f_out[(size_t)m * NOUT + col] = acc[mi][ni][j] + bv;
                }
            }
        }
    }
}

// ---------------------------------------------------------------------------
// Flash attention, swapped QK^T, QBLK=128 (proven body) with K/V
// double-buffer and SINGLE __syncthreads per tile:
//   { stage(nxt) ; compute(cur) ; __syncthreads() }
// Loads issue before the long compute phase so the barrier's drain finds
// them landed; full compiler fence semantics kept (raw s_barrier raced).
// Ps LDS exchange retained (reg-exchange via shfl_xor was measured slower:
// cross-half shfl -> ds_bpermute + selects on the busiest pipe).
// ---------------------------------------------------------------------------
__global__ __launch_bounds__(512)
void attn_kernel(const __bf16* __restrict__ qkvb, const __bf16* __restrict__ vtb,
                 __bf16* __restrict__ ctxb)
{
    constexpr int S = 1025, S2 = 1088, ROW = 3072;
    const int tid  = threadIdx.x;
    const int lane = tid & 63;
    const int w    = tid >> 6;
    const int fr   = lane & 15, fq = lane >> 4;

    const int xx = blockIdx.x & 7, jj = blockIdx.x >> 3;
    const int tile = xx * 288 + jj;
    const int bh = tile / 9;
    const int q0 = (tile % 9) * 128;
    const int bb = bh >> 4, hh = bh & 15;

    const __bf16* qp = qkvb + (size_t)(bb * 1025) * ROW + hh * 192;
    const __bf16* kp = qp + 64;
    const __bf16* vp = vtb + (size_t)bh * 64 * S2;

    __shared__ __align__(16) __bf16 Ks[2][64 * 64];
    __shared__ __align__(16) __bf16 Vs[2][64 * 64];
    __shared__ u32 Ps[8][16 * 33];

    const int r0 = tid >> 3, g0 = (tid & 7) ^ ((tid >> 3) & 7);

#define ASTAGE(nb, kv0s) { \
    int kr = (kv0s) + r0; if (kr > S - 1) kr = S - 1; \
    gload16(kp + (size_t)kr * ROW + g0 * 8, &Ks[nb][tid * 8]); \
    gload16(vp + (size_t)r0 * S2 + (kv0s) + g0 * 8, &Vs[nb][tid * 8]); }

    int qrow = q0 + w * 16 + fr; if (qrow > S - 1) qrow = S - 1;
    const bf16x8 qa0 = *(const bf16x8*)(qp + (size_t)qrow * ROW + fq * 8);
    const bf16x8 qa1 = *(const bf16x8*)(qp + (size_t)qrow * ROW + 32 + fq * 8);

    f32x4 ctx[4];
    #pragma unroll
    for (int di = 0; di < 4; ++di) ctx[di] = f32x4{0.f, 0.f, 0.f, 0.f};
    float mrow = -1e30f;
    float lrow = 0.f;

    u32* psrow_w = &Ps[w][fr * 33];

    ASTAGE(0, 0);
    __syncthreads();

    for (int kt = 0; kt < 17; ++kt) {
        const int cur = kt & 1;
        const int kv0 = kt * 64;
        if (kt + 1 < 17) ASTAGE(cur ^ 1, kv0 + 64);   // prefetch under compute

        f32x4 sc[4];
        #pragma unroll
        for (int ni = 0; ni < 4; ++ni) {
            const int row = ni * 16 + fr;
            bf16x8 kf0 = *(const bf16x8*)&Ks[cur][row * 64 + ((fq    ) ^ (row & 7)) * 8];
            bf16x8 kf1 = *(const bf16x8*)&Ks[cur][row * 64 + ((fq + 4) ^ (row & 7)) * 8];
            f32x4 z = f32x4{0.f, 0.f, 0.f, 0.f};
            z = mfma16(kf0, qa0, z);
            sc[ni] = mfma16(kf1, qa1, z);
        }
        if (kv0 + 64 > S) {
            #pragma unroll
            for (int ni = 0; ni < 4; ++ni)
                #pragma unroll
                for (int j = 0; j < 4; ++j)
                    if (kv0 + ni * 16 + fq * 4 + j >= S) sc[ni][j] = -1e30f;
        }

        float mt = sc[0][0];
        #pragma unroll
        for (int ni = 0; ni < 4; ++ni)
            #pragma unroll
            for (int j = 0; j < 4; ++j) mt = fmaxf(mt, sc[ni][j]);
        mt = fmaxf(mt, __shfl_xor(mt, 16, 64));
        mt = fmaxf(mt, __shfl_xor(mt, 32, 64));

        if (__any(mt > mrow + 8.0f)) {
            const float mnew = fmaxf(mrow, mt);
            const float alpha = exp2fast(mrow - mnew);
            mrow = mnew;
            lrow *= alpha;
            float av[4];
            #pragma unroll
            for (int j = 0; j < 4; ++j) av[j] = __shfl(alpha, fq * 4 + j, 64);
            #pragma unroll
            for (int di = 0; di < 4; ++di) {
                ctx[di][0] *= av[0]; ctx[di][1] *= av[1];
                ctx[di][2] *= av[2]; ctx[di][3] *= av[3];
            }
        }

        float p[4][4];
        float s = 0.f;
        #pragma unroll
        for (int ni = 0; ni < 4; ++ni)
            #pragma unroll
            for (int j = 0; j < 4; ++j) {
                p[ni][j] = exp2fast(sc[ni][j] - mrow);
                s += p[ni][j];
            }
        s += __shfl_xor(s, 16, 64);
        s += __shfl_xor(s, 32, 64);
        lrow += s;

        #pragma unroll
        for (int ni = 0; ni < 4; ++ni) {
            #pragma unroll
            for (int h = 0; h < 2; ++h) {
                unsigned short lo = __builtin_bit_cast(unsigned short, (__bf16)p[ni][2 * h]);
                unsigned short hi = __builtin_bit_cast(unsigned short, (__bf16)p[ni][2 * h + 1]);
                psrow_w[fq * 8 + ni * 2 + h] = (u32)lo | ((u32)hi << 16);
            }
        }
        u32x4 pav[2];
        #pragma unroll
        for (int ks = 0; ks < 2; ++ks)
            #pragma unroll
            for (int t = 0; t < 4; ++t) {
                const int slot = (2 * (fq & 1) + (t >> 1)) * 8
                               + (2 * ks + (fq >> 1)) * 2 + (t & 1);
                pav[ks][t] = psrow_w[slot];
            }

        #pragma unroll
        for (int ks = 0; ks < 2; ++ks) {
            const bf16x8 pa = __builtin_bit_cast(bf16x8, pav[ks]);
            #pragma unroll
            for (int di = 0; di < 4; ++di) {
                const int row = di * 16 + fr;
                bf16x8 vf = *(const bf16x8*)&Vs[cur][row * 64 + ((ks * 4 + fq) ^ (row & 7)) * 8];
                ctx[di] = mfma16(pa, vf, ctx[di]);
            }
        }
        __syncthreads();   // single barrier: certifies nxt loads + WAR guard
    }

    float linv[4];
    #pragma unroll
    for (int j = 0; j < 4; ++j) linv[j] = 1.0f / __shfl(lrow, fq * 4 + j, 64);
    #pragma unroll
    for (int di = 0; di < 4; ++di) {
        #pragma unroll
        for (int j = 0; j < 4; ++j) {
            const int qg = q0 + w * 16 + fq * 4 + j;
            if (qg < S) {
                ctxb[((size_t)bb * 1025 + qg) * 1024 + hh * 64 + di * 16 + fr] =
                    (__bf16)(ctx[di][j] * linv[j]);
            }
        }
    }
#undef ASTAGE
}

// ---------------------------------------------------------------------------
extern "C" void kernel_launch(void* const* d_in, const int* in_sizes, int n_in,
                              void* d_out, int out_size, void* d_ws, size_t ws_size,
                              hipStream_t stream)
{
    const float* hs      = (const float*)d_in[0];
    const float* w_qkv   = (const float*)d_in[1];
    const float* b_qkv   = (const float*)d_in[2];
    const float* w_dense = (const float*)d_in[3];
    const float* b_dense = (const float*)d_in[4];

    const size_t nHS  = (size_t)16 * 1025 * 1024;
    const size_t nWQ  = (size_t)3072 * 1024;
    const size_t nWD  = (size_t)1024 * 1024;
    const size_t nQKV = (size_t)16400 * 3072;

    __bf16* hsb     = (__bf16*)d_ws;
    __bf16* wqkvb   = hsb + nHS;
    __bf16* wdenseb = wqkvb + nWQ;
    __bf16* qkvb    = wdenseb + nWD;
    __bf16* ctxb    = qkvb + nQKV;
    __bf16* vtb     = ctxb + nHS;

    convert3_kernel<<<dim3(8200 + 1536 + 512), dim3(256), 0, stream>>>(
        hs, hsb, 8200, w_qkv, wqkvb, 1536, w_dense, wdenseb);

    gemm_big<0><<<dim3(65 * 24), dim3(512), 0, stream>>>(
        hsb, wqkvb, b_qkv, qkvb, vtb, nullptr);

    attn_kernel<<<dim3(8 * 288), dim3(512), 0, stream>>>(qkvb, vtb, ctxb);

    gemm_big<1><<<dim3(65 * 8), dim3(512), 0, stream>>>(
        ctxb, wdenseb, b_dense, nullptr, nullptr, (float*)d_out);
}